// Round 1
// baseline (1274.656 us; speedup 1.0000x reference)
//
#include <hip/hip_runtime.h>
#include <hip/hip_cooperative_groups.h>

namespace cg = cooperative_groups;

#define NB    128
#define P     512
#define PP    (P * P)          // 262144
#define TOT   (NB * PP)        // 33554432
#define EPS_F 0.1f
#define INV_EPS 10.0f
#define MAX_IT 100

// scratch layout (floats), living in the TAIL of the dist_sqr output region
#define SCR_U     0            // 65536 floats: u[n][i]
#define SCR_V     65536        // 65536 floats: v[n][j]
#define SCR_ERR   131072       // 256 floats: errA[it] (only 100 used)
#define SCR_W     131328       // 262144 floats: w[i][j]
#define SCR_FLOATS (SCR_W + PP)        // 393472
#define DIST_KEEP  (TOT - SCR_FLOATS)  // 33160960

__global__ void prep_kernel(const float* __restrict__ species,
                            float* __restrict__ scr,
                            float* __restrict__ cost_out) {
  int tid = blockIdx.x * blockDim.x + threadIdx.x;   // grid covers PP exactly
  if (tid < PP) {
    int i = tid >> 9, j = tid & (P - 1);
    const float* si = species + i * 8;
    const float* sj = species + j * 8;
    float g = 0.f;
#pragma unroll
    for (int k = 0; k < 8; ++k) g += si[k] * sj[k];
    scr[SCR_W + tid] = fabsf(1.0f / g + 1e-5f);
  }
  if (tid < NB * P) { scr[SCR_U + tid] = 0.f; scr[SCR_V + tid] = 0.f; }
  if (tid < 256) scr[SCR_ERR + tid] = 0.f;
  if (tid < NB) cost_out[tid] = 0.f;
}

__global__ void cmat_kernel(const float* __restrict__ x, const float* __restrict__ y,
                            const float* __restrict__ w,
                            float* __restrict__ Cout, float* __restrict__ dist_out) {
  int idx = blockIdx.x * blockDim.x + threadIdx.x;   // grid covers TOT exactly
  int n = idx >> 18;
  int r = idx & (PP - 1);
  int i = r >> 9, j = r & (P - 1);
  const float* xp = x + ((n << 9) + i) * 3;
  const float* yp = y + ((n << 9) + j) * 3;
  float ds = 0.f;
#pragma unroll
  for (int k = 0; k < 3; ++k) {
    float d = xp[k] - yp[k];
    float per = rintf(d) - d;    // jnp.round = round-half-to-even = rintf
    ds += per * per;
  }
  float c = ds * w[r];
  Cout[idx] = c;
  if (idx < DIST_KEEP) dist_out[idx] = ds;  // tail holds scratch; filled later
}

__global__ void tail_kernel(const float* __restrict__ x, const float* __restrict__ y,
                            float* __restrict__ dist_out) {
  int idx = DIST_KEEP + blockIdx.x * blockDim.x + threadIdx.x;
  if (idx >= TOT) return;
  int n = idx >> 18;
  int r = idx & (PP - 1);
  int i = r >> 9, j = r & (P - 1);
  const float* xp = x + ((n << 9) + i) * 3;
  const float* yp = y + ((n << 9) + j) * 3;
  float ds = 0.f;
#pragma unroll
  for (int k = 0; k < 3; ++k) {
    float d = xp[k] - yp[k];
    float per = rintf(d) - d;
    ds += per * per;
  }
  dist_out[idx] = ds;
}

__global__ __launch_bounds__(256)
void sinkhorn_kernel(const float* __restrict__ C,
                     float* __restrict__ scr,
                     float* __restrict__ pi_out,
                     float* __restrict__ cost_out) {
  cg::grid_group grid = cg::this_grid();
  const int lane = threadIdx.x & 63;
  const int wib  = threadIdx.x >> 6;                 // wave in block, 0..3
  const int gwave = (blockIdx.x << 2) | wib;
  const int nW    = gridDim.x << 2;                  // 2048 waves at grid=512

  float* u    = scr + SCR_U;
  float* v    = scr + SCR_V;
  float* errA = scr + SCR_ERR;
  __shared__ float lds[4];

  const float logmu = logf(1.0f / 512.0f + 1e-8f);   // log(mu+1e-8) == log(nu+1e-8)

  for (int it = 0; it < MAX_IT; ++it) {
    // ---------- U phase: u_new[i] = eps*(logmu - log sum_j exp((v_j - C_ij)/eps))
    float myDu = 0.f;
    for (int row = gwave; row < NB * P; row += nW) {
      const int n = row >> 9;
      const float* Crow = C + ((size_t)row << 9);
      const float* vrow = v + (n << 9);
      float acc = 0.f;
#pragma unroll
      for (int t = 0; t < 8; ++t) {
        int j = lane + (t << 6);
        acc += __expf((vrow[j] - Crow[j]) * INV_EPS);
      }
#pragma unroll
      for (int o = 32; o > 0; o >>= 1) acc += __shfl_xor(acc, o);
      if (lane == 0) {
        float un = EPS_F * (logmu - logf(acc));
        myDu += fabsf(un - u[row]);
        u[row] = un;
      }
    }
    if (lane == 0) lds[wib] = myDu;
    __syncthreads();
    if (threadIdx.x == 0) atomicAdd(&errA[it], lds[0] + lds[1] + lds[2] + lds[3]);
    grid.sync();

    // ---------- V phase: v_new[j] = eps*(logmu - log sum_i exp((u_i - C_ij)/eps))
    // chunk = (n, 32-column block); 2 lanes per column (even/odd rows)
    for (int chunk = gwave; chunk < NB * 16; chunk += nW) {
      const int n  = chunk >> 4;
      const int col = ((chunk & 15) << 5) + (lane & 31);
      const float* Cb  = C + ((size_t)n << 18);
      const float* ub  = u + (n << 9);
      float acc = 0.f;
#pragma unroll 8
      for (int i = (lane >> 5); i < P; i += 2) {
        acc += __expf((ub[i] - Cb[(i << 9) + col]) * INV_EPS);
      }
      acc += __shfl_xor(acc, 32);
      if (lane < 32) v[(n << 9) + col] = EPS_F * (logmu - logf(acc));
    }
    float sumv = errA[it];      // complete since grid.sync above; no writer now
    grid.sync();
    if ((sumv / 128.0f) < 0.1f) break;   // matches ref: update applied, then frozen
  }

  // ---------- PI phase: pi = exp((u_i + v_j - C)/eps); cost[n] = sum pi*C
  for (int row = gwave; row < NB * P; row += nW) {
    const int n = row >> 9;
    const float un = u[row];
    const float* Crow = C + ((size_t)row << 9);
    const float* vrow = v + (n << 9);
    float* Prow = pi_out + ((size_t)row << 9);
    float acc = 0.f;
#pragma unroll
    for (int t = 0; t < 8; ++t) {
      int j = lane + (t << 6);
      float c = Crow[j];
      float p = __expf((un + vrow[j] - c) * INV_EPS);
      Prow[j] = p;
      acc += p * c;
    }
#pragma unroll
    for (int o = 32; o > 0; o >>= 1) acc += __shfl_xor(acc, o);
    if (lane == 0) atomicAdd(&cost_out[n], acc);
  }
}

extern "C" void kernel_launch(void* const* d_in, const int* in_sizes, int n_in,
                              void* d_out, int out_size, void* d_ws, size_t ws_size,
                              hipStream_t stream) {
  const float* x = (const float*)d_in[0];
  const float* y = (const float*)d_in[1];
  const float* species = (const float*)d_in[2];

  float* out  = (float*)d_out;
  float* cost = out;                 // 128
  float* pi   = out + 128;           // TOT
  float* C    = pi + (size_t)TOT;    // TOT
  float* dist = C + (size_t)TOT;     // TOT
  float* scr  = dist + (size_t)DIST_KEEP;   // scratch in dist tail

  hipLaunchKernelGGL(prep_kernel, dim3(PP / 256), dim3(256), 0, stream,
                     species, scr, cost);
  hipLaunchKernelGGL(cmat_kernel, dim3(TOT / 256), dim3(256), 0, stream,
                     x, y, scr + SCR_W, C, dist);

  void* args[] = { (void*)&C, (void*)&scr, (void*)&pi, (void*)&cost };
  hipLaunchCooperativeKernel((void*)sinkhorn_kernel, dim3(512), dim3(256),
                             args, 0, stream);

  hipLaunchKernelGGL(tail_kernel, dim3(SCR_FLOATS / 256), dim3(256), 0, stream,
                     x, y, dist);
}

// Round 2
// 437.034 us; speedup vs baseline: 2.9166x; 2.9166x over previous
//
#include <hip/hip_runtime.h>
#include <hip/hip_cooperative_groups.h>

namespace cg = cooperative_groups;

#define NB    128
#define P     512
#define PP    262144            // P*P
#define TOT   33554432          // NB*PP
#define MAX_IT 100

// scratch lives in the TAIL of the dist_sqr output region (floats from scr base)
#define SCR_K      0            // bf16[TOT] = 16777216 float slots
#define SCR_W      16777216     // 262144: species weight matrix
#define SCR_CP     17039360     // 2 * 128 * 4 * 512 = 524288: col partials (dbuf)
#define SCR_U      17563648     // 65536
#define SCR_V      17629184     // 65536 (written once at end, for pi kernel)
#define SCR_ERRP   17694720     // 2 * 512 (dbuf)
#define SCR_FLOATS 17695744
#define DIST_KEEP  (TOT - SCR_FLOATS)   // 15858688 (multiple of 4)

__device__ __forceinline__ float bfbits(unsigned u) {
  union { unsigned b; float f; } x; x.b = u; return x.f;
}

__global__ void prep_kernel(const float* __restrict__ species,
                            float* __restrict__ scr, float* __restrict__ cost) {
  int tid = blockIdx.x * 256 + threadIdx.x;      // grid covers PP
  if (tid < PP) {
    int i = tid >> 9, j = tid & (P - 1);
    const float* si = species + i * 8;
    const float* sj = species + j * 8;
    float g = 0.f;
#pragma unroll
    for (int k = 0; k < 8; ++k) g += si[k] * sj[k];
    scr[SCR_W + tid] = fabsf(1.0f / g + 1e-5f);
  }
  if (tid < NB * P) scr[SCR_U + tid] = 0.f;
  if (tid < NB) cost[tid] = 0.f;
}

// 4 elements per thread: writes C (f32x4), dist (f32x4, guarded), K (bf16x4)
__global__ void cmat_kernel(const float* __restrict__ x, const float* __restrict__ y,
                            const float* __restrict__ W,
                            unsigned short* __restrict__ K,
                            float* __restrict__ C, float* __restrict__ dist) {
  int g = blockIdx.x * 256 + threadIdx.x;        // [0, TOT/4)
  int base = g << 2;
  int n = base >> 18;
  int r = base & (PP - 1);
  int i = r >> 9, j0 = r & (P - 1);
  const float* xp = x + ((n << 9) + i) * 3;
  float x0 = xp[0], x1 = xp[1], x2 = xp[2];
  const float* yp = y + ((n << 9) + j0) * 3;
  float4 w4 = *reinterpret_cast<const float4*>(W + r);
  float wv[4] = { w4.x, w4.y, w4.z, w4.w };
  float c[4], d[4];
  unsigned short kk[4];
#pragma unroll
  for (int q = 0; q < 4; ++q) {
    float dx = x0 - yp[q * 3 + 0];
    float dy = x1 - yp[q * 3 + 1];
    float dz = x2 - yp[q * 3 + 2];
    dx = rintf(dx) - dx; dy = rintf(dy) - dy; dz = rintf(dz) - dz;
    float ds = dx * dx + dy * dy + dz * dz;
    d[q] = ds;
    c[q] = ds * wv[q];
    float kf = __expf(-10.f * c[q]);
    unsigned b = __float_as_uint(kf);
    kk[q] = (unsigned short)((b + 0x7fffu + ((b >> 16) & 1u)) >> 16);   // RNE to bf16
  }
  *reinterpret_cast<float4*>(C + base) = make_float4(c[0], c[1], c[2], c[3]);
  if (base < DIST_KEEP)
    *reinterpret_cast<float4*>(dist + base) = make_float4(d[0], d[1], d[2], d[3]);
  uint2 kp;
  kp.x = (unsigned)kk[0] | ((unsigned)kk[1] << 16);
  kp.y = (unsigned)kk[2] | ((unsigned)kk[3] << 16);
  *reinterpret_cast<uint2*>(K + base) = kp;
}

// fills the dist tail that held scratch during sinkhorn
__global__ void tail_kernel(const float* __restrict__ x, const float* __restrict__ y,
                            float* __restrict__ dist) {
  int idx = DIST_KEEP + blockIdx.x * 256 + threadIdx.x;
  int n = idx >> 18;
  int r = idx & (PP - 1);
  int i = r >> 9, j = r & (P - 1);
  const float* xp = x + ((n << 9) + i) * 3;
  const float* yp = y + ((n << 9) + j) * 3;
  float ds = 0.f;
#pragma unroll
  for (int k = 0; k < 3; ++k) {
    float dd = xp[k] - yp[k];
    float per = rintf(dd) - dd;
    ds += per * per;
  }
  dist[idx] = ds;
}

// 512 blocks x 512 threads. Block b: batch n=b>>2, row-block rb=b&3 (128 rows).
// One grid.sync per iteration; v kept in LDS (recomputed redundantly+identically
// per block from global column partials -> consistent break decision).
__global__ __launch_bounds__(512, 4)
void sinkhorn_kernel(float* __restrict__ scr) {
  cg::grid_group grid = cg::this_grid();
  const unsigned short* Kus = (const unsigned short*)scr;   // SCR_K = 0
  float* u    = scr + SCR_U;
  float* cp   = scr + SCR_CP;      // [buf][n][rb][c]
  float* errP = scr + SCR_ERRP;    // [buf][bid]

  const int tid  = threadIdx.x;
  const int lane = tid & 63;
  const int wid  = tid >> 6;                // 0..7
  const int bid  = blockIdx.x;
  const int n    = bid >> 2;
  const int rb   = bid & 3;
  const int row0 = (n << 9) + (rb << 7);    // 128 rows per block, 16 per wave

  __shared__ float vLDS[512];
  __shared__ float colsum[512];
  __shared__ float red[512];
  __shared__ float wdu[8];

  vLDS[tid] = 0.f;
  __syncthreads();

  const float logmu = logf(1.0f / 512.0f + 1e-8f);

  for (int it = 0; it < MAX_IT; ++it) {
    const int buf = it & 1;
    float ev[8], colacc[8];
#pragma unroll
    for (int t = 0; t < 8; ++t) {
      ev[t] = __expf(10.f * vLDS[(lane << 3) + t]);
      colacc[t] = 0.f;
    }
    colsum[tid] = 0.f;
    __syncthreads();

    float myDu = 0.f;
#pragma unroll 2
    for (int r = 0; r < 16; ++r) {
      int row = row0 + (wid << 4) + r;
      const uint4* kp = reinterpret_cast<const uint4*>(Kus + ((size_t)row << 9) + (lane << 3));
      uint4 kw = *kp;
      float k[8];
      k[0] = bfbits(kw.x << 16); k[1] = bfbits(kw.x & 0xffff0000u);
      k[2] = bfbits(kw.y << 16); k[3] = bfbits(kw.y & 0xffff0000u);
      k[4] = bfbits(kw.z << 16); k[5] = bfbits(kw.z & 0xffff0000u);
      k[6] = bfbits(kw.w << 16); k[7] = bfbits(kw.w & 0xffff0000u);
      float s = 0.f;
#pragma unroll
      for (int t = 0; t < 8; ++t) s = fmaf(k[t], ev[t], s);
#pragma unroll
      for (int o = 32; o > 0; o >>= 1) s += __shfl_xor(s, o);
      float uo = u[row];                         // broadcast load
      float un = 0.1f * (logmu - __logf(s));
      myDu += fabsf(un - uo);
      if (lane == 0) u[row] = un;
      float eu = __expf(10.f * un);
#pragma unroll
      for (int t = 0; t < 8; ++t) colacc[t] = fmaf(k[t], eu, colacc[t]);
    }
#pragma unroll
    for (int t = 0; t < 8; ++t) atomicAdd(&colsum[(lane << 3) + t], colacc[t]);
    if (lane == 0) wdu[wid] = myDu;
    __syncthreads();

    cp[(buf << 18) + (n << 11) + (rb << 9) + tid] = colsum[tid];
    if (tid == 0) {
      float e = 0.f;
#pragma unroll
      for (int w = 0; w < 8; ++w) e += wdu[w];
      errP[(buf << 9) + bid] = e;
    }
    grid.sync();

    // v-reduce (redundant per block, deterministic identical order)
    float sc = 0.f;
#pragma unroll
    for (int q = 0; q < 4; ++q) sc += cp[(buf << 18) + (n << 11) + (q << 9) + tid];
    float vc = 0.1f * (logmu - __logf(sc));

    red[tid] = errP[(buf << 9) + tid];
    __syncthreads();
#pragma unroll
    for (int o = 256; o > 0; o >>= 1) {
      if (tid < o) red[tid] += red[tid + o];
      __syncthreads();
    }
    float errTot = red[0];
    vLDS[tid] = vc;
    __syncthreads();
    if (errTot < 12.8f) break;     // errTot/128 < 0.1 ; update already applied
  }

  if (rb == 0) scr[SCR_V + (n << 9) + tid] = vLDS[tid];
}

// pi = exp((u_i + v_j - C)/eps); cost[n] += pi*C. 8 elems/thread, 1 row/wave.
__global__ __launch_bounds__(256)
void pi_kernel(const float* __restrict__ C, const float* __restrict__ scr,
               float* __restrict__ pi, float* __restrict__ cost) {
  int gid = blockIdx.x * 256 + threadIdx.x;   // [0, TOT/8)
  int lane = threadIdx.x & 63;
  int row = gid >> 6;
  int n = row >> 9;
  int c0 = lane << 3;
  float uu = scr[SCR_U + row];
  const float* vp = scr + SCR_V + (n << 9) + c0;
  float4 va = *reinterpret_cast<const float4*>(vp);
  float4 vb = *reinterpret_cast<const float4*>(vp + 4);
  const float* Cr = C + ((size_t)row << 9) + c0;
  float4 ca = *reinterpret_cast<const float4*>(Cr);
  float4 cb = *reinterpret_cast<const float4*>(Cr + 4);
  float4 pa, pb;
  pa.x = __expf((uu + va.x - ca.x) * 10.f);
  pa.y = __expf((uu + va.y - ca.y) * 10.f);
  pa.z = __expf((uu + va.z - ca.z) * 10.f);
  pa.w = __expf((uu + va.w - ca.w) * 10.f);
  pb.x = __expf((uu + vb.x - cb.x) * 10.f);
  pb.y = __expf((uu + vb.y - cb.y) * 10.f);
  pb.z = __expf((uu + vb.z - cb.z) * 10.f);
  pb.w = __expf((uu + vb.w - cb.w) * 10.f);
  float* Pr = pi + ((size_t)row << 9) + c0;
  *reinterpret_cast<float4*>(Pr) = pa;
  *reinterpret_cast<float4*>(Pr + 4) = pb;
  float acc = pa.x * ca.x + pa.y * ca.y + pa.z * ca.z + pa.w * ca.w
            + pb.x * cb.x + pb.y * cb.y + pb.z * cb.z + pb.w * cb.w;
#pragma unroll
  for (int o = 32; o > 0; o >>= 1) acc += __shfl_xor(acc, o);
  __shared__ float ws[4];
  if (lane == 0) ws[threadIdx.x >> 6] = acc;
  __syncthreads();
  if (threadIdx.x == 0) atomicAdd(cost + n, ws[0] + ws[1] + ws[2] + ws[3]);
}

extern "C" void kernel_launch(void* const* d_in, const int* in_sizes, int n_in,
                              void* d_out, int out_size, void* d_ws, size_t ws_size,
                              hipStream_t stream) {
  const float* x = (const float*)d_in[0];
  const float* y = (const float*)d_in[1];
  const float* species = (const float*)d_in[2];

  float* out  = (float*)d_out;
  float* cost = out;                     // 128
  float* pi   = out + 128;               // TOT
  float* C    = pi + (size_t)TOT;        // TOT
  float* dist = C + (size_t)TOT;         // TOT
  float* scr  = dist + (size_t)DIST_KEEP;

  hipLaunchKernelGGL(prep_kernel, dim3(PP / 256), dim3(256), 0, stream,
                     species, scr, cost);
  hipLaunchKernelGGL(cmat_kernel, dim3(TOT / 4 / 256), dim3(256), 0, stream,
                     x, y, scr + SCR_W, (unsigned short*)scr, C, dist);

  void* args[] = { (void*)&scr };
  hipLaunchCooperativeKernel((void*)sinkhorn_kernel, dim3(512), dim3(512),
                             args, 0, stream);

  hipLaunchKernelGGL(pi_kernel, dim3(TOT / 8 / 256), dim3(256), 0, stream,
                     C, scr, pi, cost);
  hipLaunchKernelGGL(tail_kernel, dim3(SCR_FLOATS / 256), dim3(256), 0, stream,
                     x, y, dist);
}